// Round 14
// baseline (48.995 us; speedup 1.0000x reference)
//
#include <hip/hip_runtime.h>
#include <hip/hip_bf16.h>
#include <hip/hip_fp16.h>

// Problem constants (B=4, C=256, H=W=64, hs=ws=32, rate=2, vk=4, pad=1)
#define BB 4
#define CC 256
#define HH 64
#define WW 64
#define QRN 1024
#define KN  1024
#define KDIM 1152            // 33*33 = 1089 padded to 18*64 (BK=64 steps)
#define TROWS 1089           // 33*33 combined-score rows per b

typedef _Float16 f16x8 __attribute__((ext_vector_type(8)));
typedef float f32x4 __attribute__((ext_vector_type(4)));
typedef float f32x16 __attribute__((ext_vector_type(16)));

#define TP_ELEMS ((size_t)BB * TROWS * KDIM)   // 5,018,112 halves (10.0 MB)
#define BP_ELEMS ((size_t)16 * CC * KDIM)      // 4,718,592 halves (9.4 MB)

// ===========================================================================
// FAST PATH
// ===========================================================================

// One qr row of the combined-score tensor T (all 1152 k, 5 chunks/thread).
// T[b][qr=Qa*33+Ra][k=(mp,np)] =
//   sum_{dq,dr in {0,1}} [masks] s[b][(Qa-dq)*32+(Ra-dr)][(mp-dq)*32+(np-dr)]
// Pad region k>=1089 -> all masks false -> 0 (required: gemm multiplies it).
__device__ __forceinline__
void process_qr(const float* __restrict__ sb, _Float16* __restrict__ T,
                int b, int qr, int t) {
    const int Qa = (qr * 993) >> 15;        // qr/33 (exact for qr<2048)
    const int Ra = qr - 33 * Qa;
    const bool q0 = (Qa < 32), q1 = (Qa >= 1);        // block-uniform
    const bool r0 = (Ra < 32), r1 = (Ra >= 1);        // block-uniform
    const float* rb00 = sb + ((size_t)((Qa)     * 32 + (Ra)))     * KN;
    const float* rb01 = sb + ((size_t)((Qa)     * 32 + (Ra - 1))) * KN;
    const float* rb10 = sb + ((size_t)((Qa - 1) * 32 + (Ra)))     * KN;
    const float* rb11 = sb + ((size_t)((Qa - 1) * 32 + (Ra - 1))) * KN;
    _Float16* trow = T + ((size_t)b * TROWS + qr) * KDIM;

    float v[5];
    #pragma unroll
    for (int j = 0; j < 5; ++j) {
        const int k = j * 256 + t;
        v[j] = 0.f;
        if (k < KDIM) {
            const int mp = (k * 993) >> 15;  // k/33 (exact for k<2048)
            const int np = k - 33 * mp;
            const bool m0 = (mp < 32), m1 = (mp >= 1) && (mp < 33);
            const bool n0 = (np < 32), n1 = (np >= 1);
            const int col = (mp << 5) + np;
            if (q0 & r0 & m0 & n0) v[j] += rb00[col];
            if (q0 & r1 & m0 & n1) v[j] += rb01[col - 1];
            if (q1 & r0 & m1 & n0) v[j] += rb10[col - 32];
            if (q1 & r1 & m1 & n1) v[j] += rb11[col - 33];
        }
    }
    #pragma unroll
    for (int j = 0; j < 5; ++j) {
        const int k = j * 256 + t;
        if (k < KDIM) trow[k] = (_Float16)v[j];
    }
}

// Merged builder: T part (2 qr rows per block -> 40 in-flight loads/thread,
// adjacent qr share 2 of 4 scores rows) + B part (x gather).
// Bijective XCD-chunk swizzle keeps all shifted readers of each scores
// element on one XCD's L2.
// Per b: 545 T blocks + 160 B blocks (4 cls x 8 cgroups x 5 k-chunks).
#define T_BLOCKS 545
#define PER_B    705
#define TB_NWG   (BB * PER_B)    // 2820

__global__ __launch_bounds__(256)
void build_TB(const float* __restrict__ s, const float* __restrict__ x,
              _Float16* __restrict__ T, _Float16* __restrict__ Bp) {
    // bijective XCD chunk remap (m204 form; nwg % 8 = 4)
    const int orig = blockIdx.x;
    const int xcd = orig & 7, pos = orig >> 3;
    const int q = TB_NWG / 8, r = TB_NWG % 8;            // 352, 4
    const int wgid =
        (xcd < r ? xcd * (q + 1) : r * (q + 1) + (xcd - r) * q) + pos;

    const int b = wgid / PER_B;
    const int rem = wgid - b * PER_B;
    const int t = threadIdx.x;

    if (rem < T_BLOCKS) {
        const float* sb = s + (size_t)b * QRN * KN;
        const int qr0 = rem * 2;
        process_qr(sb, T, b, qr0, t);
        if (qr0 + 1 < TROWS) process_qr(sb, T, b, qr0 + 1, t);
    } else {
        // ---------------- B part: Bp[bc][c][k] = gathered x ---------------
        const int u = rem - T_BLOCKS;           // [0,160)
        const int rest = u / 5;
        const int kc = u - rest * 5;
        const int cls = rest >> 3, cg = rest & 7;
        const int k = kc * 256 + t;
        if (k >= KDIM) return;
        const int ph = cls >> 1, pw = cls & 1;
        const int ua = 1 - ph, va = 1 - pw;
        const int bc = b * 4 + cls;

        const int mp = (k * 993) >> 15;
        const int np = k - 33 * mp;
        int rr = 2 * mp + ua - 1; rr = min(max(rr, 0), HH - 1);
        int cc2 = 2 * np + va - 1; cc2 = min(max(cc2, 0), WW - 1);
        const int off = rr * WW + cc2;

        const float* xb = x + ((size_t)b * CC + cg * 32) * HH * WW;
        _Float16* bpb = Bp + ((size_t)bc * CC + cg * 32) * KDIM + k;

        #pragma unroll 8
        for (int i = 0; i < 32; ++i) {
            bpb[(size_t)i * KDIM] = (_Float16)xb[(size_t)i * HH * WW + off];
        }
    }
}

// GEMM per (b,class): D[c][px] = sum_k Bp[c][k] * T[b][trow(px,cls)][k]
// Tile 64(c) x 128(px), 512 blocks (2/CU). 4 waves = 2(n-half) x 2(k-slice).
// BK=64 per step (18 steps, half the barriers of BK=32): per wave-step
// 8 ds_read_b128 : 8 mfma_32x32x16 (1.0 ratio). PF=2 register ring
// (static via full unroll), double-buffered LDS (50 KB), raw s_barrier +
// lgkmcnt(0) (global loads stay in flight), setprio(1) around MFMA (T5).
// After K-loop: k-slices reduced across wave pairs via LDS; ks=0 waves do
// the epilogue out = ori_x + 0.25*alpha*D (each output pixel exactly once).
#define A_SLOT 520               // 64*8 + 8 halves per 8-k slot
#define B_SLOT 1040              // 128*8 + 8 halves
#define A_BUF  (8 * A_SLOT)      // 4160 halves per buffer
#define B_BUF  (8 * B_SLOT)      // 8320 halves
#define NSTEP  18                // KDIM/64
__global__ __launch_bounds__(256)
void gemm_f16(const _Float16* __restrict__ T,    // [4][1089][1152] (px side)
              const _Float16* __restrict__ Bp,   // [16][256][1152] (c side)
              const float* __restrict__ orix,
              const float* __restrict__ alphap,
              float* __restrict__ out) {
    __shared__ __align__(16) char smem[49920];   // stage 49920 B >= ex 32768 B
    _Float16* AmB = (_Float16*)smem;             // [2][A_BUF]
    _Float16* BnB = AmB + 2 * A_BUF;             // [2][B_BUF]
    float*    ex  = (float*)smem;                // k-reduction overlay

    // XCD-grouping remap: XCD r gets 64 consecutive wids = 2 bc panels
    const int lin = blockIdx.x + 4 * (blockIdx.y + 8 * blockIdx.z); // 0..511
    const int wid = (lin & 7) * 64 + (lin >> 3);
    const int bc  = wid >> 5;
    const int byy = (wid >> 2) & 7;
    const int bxx = wid & 3;

    const int b = bc >> 2, cls = bc & 3;
    const int ph = cls >> 1, pw = cls & 1;
    const int c0  = bxx * 64;
    const int px0 = byy * 128;

    const int t = threadIdx.x;
    const int wv = t >> 6, l = t & 63;
    const int lr = l & 31;                // row within 32-tile
    const int lh = l >> 5;                // k-half selector (8-k granules)
    const int wc = wv & 1;                // n-half (which 64 of 128 px)
    const int ks = wv >> 1;               // k-slice (which 32 of BK=64)

    const _Float16* Ag = Bp + ((size_t)bc * CC + c0) * KDIM;   // M operand
    const _Float16* Tg = T + (size_t)b * TROWS * KDIM;         // N operand

    // staging decomposition: thread covers A rows {st_r, st_r+32} and
    // B rows {st_r, st_r+32, st_r+64, st_r+96}, all at k-slot st_slot.
    const int st_r    = t >> 3;           // 0..31
    const int st_slot = t & 7;
    const int kb0     = st_slot * 8;
    int trowv[4];
    #pragma unroll
    for (int r2 = 0; r2 < 4; ++r2) {
        const int px = px0 + r2 * 32 + st_r;
        trowv[r2] = ((px >> 5) + ph) * 33 + (px & 31) + pw;
    }

    f32x16 acc[2][2];
    #pragma unroll
    for (int i = 0; i < 2; ++i)
        #pragma unroll
        for (int j = 0; j < 2; ++j)
            acc[i][j] = (f32x16)(0.f);

    f16x8 rga[2][2], rgb[2][4];

    // ---- prologue: issue loads for steps 0,1; write step 0 into buf 0
    #pragma unroll
    for (int s2 = 0; s2 < 2; ++s2) {
        const size_t kb = (size_t)s2 * 64 + kb0;
        rga[s2][0] = *reinterpret_cast<const f16x8*>(Ag + (size_t)st_r * KDIM + kb);
        rga[s2][1] = *reinterpret_cast<const f16x8*>(Ag + (size_t)(st_r + 32) * KDIM + kb);
        #pragma unroll
        for (int r2 = 0; r2 < 4; ++r2)
            rgb[s2][r2] = *reinterpret_cast<const f16x8*>(
                Tg + (size_t)trowv[r2] * KDIM + kb);
    }
    *reinterpret_cast<f16x8*>(&AmB[st_slot * A_SLOT + st_r * 8]) = rga[0][0];
    *reinterpret_cast<f16x8*>(&AmB[st_slot * A_SLOT + (st_r + 32) * 8]) = rga[0][1];
    #pragma unroll
    for (int r2 = 0; r2 < 4; ++r2)
        *reinterpret_cast<f16x8*>(
            &BnB[st_slot * B_SLOT + (r2 * 32 + st_r) * 8]) = rgb[0][r2];
    asm volatile("s_waitcnt lgkmcnt(0)" ::: "memory");
    __builtin_amdgcn_s_barrier();

    #pragma unroll
    for (int ts = 0; ts < NSTEP; ++ts) {
        const int cur = ts & 1;
        // issue loads for step ts+2 into the ring slot just drained
        if (ts + 2 < NSTEP) {
            const int sl = ts & 1;
            const size_t kb = (size_t)(ts + 2) * 64 + kb0;
            rga[sl][0] = *reinterpret_cast<const f16x8*>(Ag + (size_t)st_r * KDIM + kb);
            rga[sl][1] = *reinterpret_cast<const f16x8*>(Ag + (size_t)(st_r + 32) * KDIM + kb);
            #pragma unroll
            for (int r2 = 0; r2 < 4; ++r2)
                rgb[sl][r2] = *reinterpret_cast<const f16x8*>(
                    Tg + (size_t)trowv[r2] * KDIM + kb);
        }

        // compute on buf[cur]: wave's 32-k slice = slots [ks*4, ks*4+4)
        f16x8 af[2][2], bf[2][2];
        #pragma unroll
        for (int kk = 0; kk < 2; ++kk) {
            const int slot = ks * 4 + kk * 2 + lh;
            #pragma unroll
            for (int mt = 0; mt < 2; ++mt)
                af[mt][kk] = *reinterpret_cast<const f16x8*>(
                    &AmB[cur * A_BUF + slot * A_SLOT + (mt * 32 + lr) * 8]);
            #pragma unroll
            for (int nt2 = 0; nt2 < 2; ++nt2)
                bf[nt2][kk] = *reinterpret_cast<const f16x8*>(
                    &BnB[cur * B_BUF + slot * B_SLOT +
                         (wc * 64 + nt2 * 32 + lr) * 8]);
        }
        __builtin_amdgcn_s_setprio(1);
        #pragma unroll
        for (int kk = 0; kk < 2; ++kk)
            #pragma unroll
            for (int mt = 0; mt < 2; ++mt)
                #pragma unroll
                for (int nt2 = 0; nt2 < 2; ++nt2)
                    acc[mt][nt2] = __builtin_amdgcn_mfma_f32_32x32x16_f16(
                        af[mt][kk], bf[nt2][kk], acc[mt][nt2], 0, 0, 0);
        __builtin_amdgcn_s_setprio(0);

        // write step ts+1 (ring slot (ts+1)&1) into the other buffer;
        // compiler inserts the precise vmcnt for these regs (never 0-drain)
        if (ts + 1 < NSTEP) {
            const int ns = (ts + 1) & 1, nb = cur ^ 1;
            *reinterpret_cast<f16x8*>(
                &AmB[nb * A_BUF + st_slot * A_SLOT + st_r * 8]) = rga[ns][0];
            *reinterpret_cast<f16x8*>(
                &AmB[nb * A_BUF + st_slot * A_SLOT + (st_r + 32) * 8]) = rga[ns][1];
            #pragma unroll
            for (int r2 = 0; r2 < 4; ++r2)
                *reinterpret_cast<f16x8*>(
                    &BnB[nb * B_BUF + st_slot * B_SLOT +
                         (r2 * 32 + st_r) * 8]) = rgb[ns][r2];
        }
        asm volatile("s_waitcnt lgkmcnt(0)" ::: "memory");
        __builtin_amdgcn_s_barrier();
    }

    // ---- cross-wave k-slice reduction: ks=1 waves dump, ks=0 waves add.
    if (ks == 1) {
        #pragma unroll
        for (int mt = 0; mt < 2; ++mt)
            #pragma unroll
            for (int nt2 = 0; nt2 < 2; ++nt2)
                #pragma unroll
                for (int r2 = 0; r2 < 16; ++r2)
                    ex[((((mt * 2 + nt2) * 2 + wc) * 16) + r2) * 64 + l] =
                        acc[mt][nt2][r2];
    }
    asm volatile("s_waitcnt lgkmcnt(0)" ::: "memory");
    __builtin_amdgcn_s_barrier();

    if (ks == 0) {
        const float scale = 0.25f * alphap[0];
        #pragma unroll
        for (int mt = 0; mt < 2; ++mt) {
            #pragma unroll
            for (int nt2 = 0; nt2 < 2; ++nt2) {
                #pragma unroll
                for (int r2 = 0; r2 < 16; ++r2) {
                    float vsum = acc[mt][nt2][r2] +
                        ex[((((mt * 2 + nt2) * 2 + wc) * 16) + r2) * 64 + l];
                    int c  = c0 + mt * 32 + (r2 & 3) + 8 * (r2 >> 2) + 4 * lh;
                    int px = px0 + wc * 64 + nt2 * 32 + lr;
                    int hh = px >> 5, ww2 = px & 31;
                    int h = 2 * hh + ph, wp = 2 * ww2 + pw;
                    size_t idx = (((size_t)b * CC + c) * HH + h) * WW + wp;
                    out[idx] = orix[idx] + scale * vsum;
                }
            }
        }
    }
}

// ===========================================================================
// FALLBACK PATH (round-1 kernels, used only if ws too small)
// ===========================================================================
#define TILE_M 64
#define TILE_N 64
#define TILE_K 16

__global__ void copy_kernel(const float* __restrict__ src,
                            float* __restrict__ dst, int n4) {
    int i = blockIdx.x * blockDim.x + threadIdx.x;
    if (i < n4)
        reinterpret_cast<float4*>(dst)[i] =
            reinterpret_cast<const float4*>(src)[i];
}

__global__ void transpose_kernel(const float* __restrict__ x,
                                 float* __restrict__ xT) {
    __shared__ float tile[32][33];
    int bh = blockIdx.z;
    int b = bh >> 6, h = bh & 63;
    int c0 = blockIdx.y * 32, w0 = blockIdx.x * 32;
    int tw = threadIdx.x & 31;
    int tc = threadIdx.x >> 5;
    #pragma unroll
    for (int i = 0; i < 4; ++i) {
        int c = tc + i * 8;
        tile[c][tw] = x[(((size_t)b * CC + c0 + c) * HH + h) * WW + w0 + tw];
    }
    __syncthreads();
    int tcw = threadIdx.x & 31;
    int twr = threadIdx.x >> 5;
    #pragma unroll
    for (int i = 0; i < 4; ++i) {
        int w = twr + i * 8;
        xT[(((size_t)b * HH + h) * WW + w0 + w) * CC + c0 + tcw] = tile[tcw][w];
    }
}

__global__ __launch_bounds__(256)
void pgemm_scatter(const float* __restrict__ scores,
                   const float* __restrict__ xT,
                   const float* __restrict__ x,
                   const float* __restrict__ alpha,
                   float* __restrict__ out,
                   int use_xt) {
    __shared__ float As[TILE_K][TILE_M];
    __shared__ float Bs[TILE_K][TILE_N];

    const int b      = blockIdx.z;
    const int tile_n = blockIdx.x;
    const int m0     = blockIdx.y * TILE_M;
    const int uv     = tile_n >> 2;
    const int u      = uv >> 2, v = uv & 3;
    const int c0     = (tile_n & 3) * 64;

    const int t  = threadIdx.x;
    const int tx = t & 15;
    const int ty = t >> 4;

    float acc[4][4] = {};
    const float* sb = scores + (size_t)b * QRN * KN;

    for (int k0 = 0; k0 < KN; k0 += TILE_K) {
        {
            int mr = t >> 2;
            int kc = (t & 3) * 4;
            float4 av = *reinterpret_cast<const float4*>(
                sb + (size_t)(m0 + mr) * KN + k0 + kc);
            As[kc + 0][mr] = av.x;
            As[kc + 1][mr] = av.y;
            As[kc + 2][mr] = av.z;
            As[kc + 3][mr] = av.w;
        }
        {
            int kr = t >> 4;
            int kg = k0 + kr;
            int m  = kg >> 5, n = kg & 31;
            int rr = 2 * m + u - 1; rr = min(max(rr, 0), HH - 1);
            int cc = 2 * n + v - 1; cc = min(max(cc, 0), WW - 1);
            int ccol = (t & 15) * 4;
            if (use_xt) {
                float4 bv = *reinterpret_cast<const float4*>(
                    xT + ((((size_t)b * HH + rr) * WW + cc) * CC) + c0 + ccol);
                Bs[kr][ccol + 0] = bv.x;
                Bs[kr][ccol + 1] = bv.y;
                Bs[kr][ccol + 2] = bv.z;
                Bs[kr][ccol + 3] = bv.w;
            } else {
                #pragma unroll
                for (int j = 0; j < 4; ++j) {
                    int c = c0 + ccol + j;
                    Bs[kr][ccol + j] =
                        x[(((size_t)b * CC + c) * HH + rr) * WW + cc];
                }
            }
        }
        __syncthreads();

        #pragma unroll
        for (int k = 0; k < TILE_K; ++k) {
            float a4[4], b4[4];
            *reinterpret_cast<float4*>(a4) =
                *reinterpret_cast<const float4*>(&As[k][ty * 4]);
            *reinterpret_cast<float4*>(b4) =
                *reinterpret_cast<const float4*>(&Bs[k][tx * 4]);
            #pragma unroll
            for (int i = 0; i < 4; ++i)
                #pragma unroll
                for (int j = 0; j < 4; ++j)
                    acc[i][j] += a4[i] * b4[j];
        }
        __syncthreads();
    }

    const float scale = alpha[0] * 0.25f;
    #pragma unroll
    for (int i = 0; i < 4; ++i) {
        int qr = m0 + ty * 4 + i;
        int Q = qr >> 5, R = qr & 31;
        int h = 2 * Q + u - 1;
        int w = 2 * R + v - 1;
        if (h < 0 || h >= HH || w < 0 || w >= WW) continue;
        #pragma unroll
        for (int j = 0; j < 4; ++j) {
            int c = c0 + tx * 4 + j;
            atomicAdd(&out[(((size_t)b * CC + c) * HH + h) * WW + w],
                      acc[i][j] * scale);
        }
    }
}

// ===========================================================================
extern "C" void kernel_launch(void* const* d_in, const int* in_sizes, int n_in,
                              void* d_out, int out_size, void* d_ws,
                              size_t ws_size, hipStream_t stream) {
    const float* ori_x  = (const float*)d_in[0];
    const float* scores = (const float*)d_in[1];
    const float* alpha  = (const float*)d_in[2];
    float* out = (float*)d_out;

    const size_t need_fast = (TP_ELEMS + BP_ELEMS) * sizeof(_Float16);

    if (ws_size >= need_fast) {
        _Float16* T  = (_Float16*)d_ws;
        _Float16* Bp = T + TP_ELEMS;

        build_TB<<<dim3(TB_NWG), 256, 0, stream>>>(scores, ori_x, T, Bp);
        gemm_f16<<<dim3(4, 8, 16), 256, 0, stream>>>(T, Bp, ori_x, alpha, out);
    } else {
        float* xT = (float*)d_ws;
        const size_t xt_bytes = (size_t)BB * HH * WW * CC * sizeof(float);
        const int use_xt = (ws_size >= xt_bytes) ? 1 : 0;

        copy_kernel<<<(BB * CC * HH * WW / 4 + 255) / 256, 256, 0, stream>>>(
            ori_x, out, BB * CC * HH * WW / 4);
        if (use_xt)
            transpose_kernel<<<dim3(WW / 32, CC / 32, BB * HH), 256, 0,
                               stream>>>(ori_x, xT);
        pgemm_scatter<<<dim3(16, 16, BB), 256, 0, stream>>>(
            scores, xT, ori_x, alpha, out, use_xt);
    }
}